// Round 1
// baseline (854.332 us; speedup 1.0000x reference)
//
#include <hip/hip_runtime.h>
#include <math.h>

#define N_REL  8
#define IN_CH  16
#define HID_CH 32
#define OUT_CH 2

// ---------------------------------------------------------------------------
// Pass 1: per-(dst, rel) edge counts
// ---------------------------------------------------------------------------
__global__ void count_kernel(const int* __restrict__ dst,
                             const int* __restrict__ rel,
                             int* __restrict__ cnt, int E) {
    int e = blockIdx.x * blockDim.x + threadIdx.x;
    if (e < E) atomicAdd(&cnt[dst[e] * N_REL + rel[e]], 1);
}

// ---------------------------------------------------------------------------
// Layer 1 edge scatter: 32 threads per edge, one per hidden channel.
// h_agg[dst][c] += (x[src] @ W1[rel])[c] / cnt(dst,rel)
// ---------------------------------------------------------------------------
__global__ void l1_edge_kernel(const float* __restrict__ x,
                               const int* __restrict__ src,
                               const int* __restrict__ dst,
                               const int* __restrict__ rel,
                               const int* __restrict__ cnt,
                               const float* __restrict__ W1,
                               float* __restrict__ h_agg, int E) {
    __shared__ float sW[N_REL * IN_CH * HID_CH];   // 16 KB
    for (int i = threadIdx.x; i < N_REL * IN_CH * HID_CH; i += blockDim.x)
        sW[i] = W1[i];
    __syncthreads();

    long gid = (long)blockIdx.x * blockDim.x + threadIdx.x;
    long e = gid >> 5;          // edge index
    int  c = (int)(gid & 31);   // hidden channel
    if (e >= E) return;

    int s = src[e], d = dst[e], r = rel[e];
    int cn = cnt[d * N_REL + r];
    float norm = 1.0f / (float)(cn > 0 ? cn : 1);

    const float* xv = x + (long)s * IN_CH;          // 64B, broadcast across 32 lanes
    const float* w  = sW + r * IN_CH * HID_CH + c;  // stride HID_CH: conflict-free

    float acc = 0.0f;
#pragma unroll
    for (int f = 0; f < IN_CH; ++f)
        acc += xv[f] * w[f * HID_CH];

    atomicAdd(&h_agg[(long)d * HID_CH + c], acc * norm);
}

// ---------------------------------------------------------------------------
// Layer 1 node: h = relu(h_agg + x @ root1 + b1), in place on h_agg.
// 32 threads per node, one per hidden channel.
// ---------------------------------------------------------------------------
__global__ void l1_node_kernel(const float* __restrict__ x,
                               const float* __restrict__ root1,
                               const float* __restrict__ b1,
                               float* __restrict__ h, int N) {
    long gid = (long)blockIdx.x * blockDim.x + threadIdx.x;
    long n = gid >> 5;
    int  c = (int)(gid & 31);
    if (n >= N) return;

    const float* xv = x + n * IN_CH;
    float acc = h[n * HID_CH + c] + b1[c];
#pragma unroll
    for (int f = 0; f < IN_CH; ++f)
        acc += xv[f] * root1[f * HID_CH + c];
    h[n * HID_CH + c] = fmaxf(acc, 0.0f);
}

// ---------------------------------------------------------------------------
// Layer 2 edge scatter: 1 thread per edge (OUT_CH = 2).
// out[dst][:] += (h[src] @ W2[rel]) / cnt(dst,rel)
// ---------------------------------------------------------------------------
__global__ void l2_edge_kernel(const float* __restrict__ h,
                               const int* __restrict__ src,
                               const int* __restrict__ dst,
                               const int* __restrict__ rel,
                               const int* __restrict__ cnt,
                               const float* __restrict__ W2,
                               float* __restrict__ out, int E) {
    __shared__ float sW[N_REL * HID_CH * OUT_CH];   // 2 KB
    for (int i = threadIdx.x; i < N_REL * HID_CH * OUT_CH; i += blockDim.x)
        sW[i] = W2[i];
    __syncthreads();

    int e = blockIdx.x * blockDim.x + threadIdx.x;
    if (e >= E) return;

    int s = src[e], d = dst[e], r = rel[e];
    int cn = cnt[d * N_REL + r];
    float norm = 1.0f / (float)(cn > 0 ? cn : 1);

    const float* hv = h + (long)s * HID_CH;         // 128B contiguous per lane
    const float* w  = sW + r * HID_CH * OUT_CH;

    float o0 = 0.0f, o1 = 0.0f;
#pragma unroll
    for (int f = 0; f < HID_CH; ++f) {
        float hf = hv[f];
        o0 += hf * w[f * OUT_CH + 0];
        o1 += hf * w[f * OUT_CH + 1];
    }
    atomicAdd(&out[(long)d * OUT_CH + 0], o0 * norm);
    atomicAdd(&out[(long)d * OUT_CH + 1], o1 * norm);
}

// ---------------------------------------------------------------------------
// Layer 2 node: out = log_softmax(out_agg + h @ root2 + b2), in place.
// 1 thread per node.
// ---------------------------------------------------------------------------
__global__ void l2_node_kernel(const float* __restrict__ h,
                               const float* __restrict__ root2,
                               const float* __restrict__ b2,
                               float* __restrict__ out, int N) {
    int n = blockIdx.x * blockDim.x + threadIdx.x;
    if (n >= N) return;

    const float* hv = h + (long)n * HID_CH;
    float o0 = out[(long)n * OUT_CH + 0] + b2[0];
    float o1 = out[(long)n * OUT_CH + 1] + b2[1];
#pragma unroll
    for (int f = 0; f < HID_CH; ++f) {
        float hf = hv[f];
        o0 += hf * root2[f * OUT_CH + 0];
        o1 += hf * root2[f * OUT_CH + 1];
    }
    float m = fmaxf(o0, o1);
    float l = m + logf(__expf(o0 - m) + __expf(o1 - m));
    out[(long)n * OUT_CH + 0] = o0 - l;
    out[(long)n * OUT_CH + 1] = o1 - l;
}

// ---------------------------------------------------------------------------
extern "C" void kernel_launch(void* const* d_in, const int* in_sizes, int n_in,
                              void* d_out, int out_size, void* d_ws, size_t ws_size,
                              hipStream_t stream) {
    const float* x     = (const float*)d_in[0];
    const int*   eidx  = (const int*)d_in[1];
    const int*   etype = (const int*)d_in[2];
    const float* W1    = (const float*)d_in[3];
    const float* root1 = (const float*)d_in[4];
    const float* b1    = (const float*)d_in[5];
    const float* W2    = (const float*)d_in[6];
    const float* root2 = (const float*)d_in[7];
    const float* b2    = (const float*)d_in[8];
    float* out = (float*)d_out;

    const int N = in_sizes[0] / IN_CH;
    const int E = in_sizes[2];
    const int* src = eidx;
    const int* dst = eidx + E;

    // workspace layout: [ cnt: N*N_REL ints | h: N*HID_CH floats ]
    int*   cnt = (int*)d_ws;
    size_t cnt_bytes = (size_t)N * N_REL * sizeof(int);
    float* h = (float*)((char*)d_ws + cnt_bytes);
    size_t h_bytes = (size_t)N * HID_CH * sizeof(float);

    hipMemsetAsync(cnt, 0, cnt_bytes, stream);
    hipMemsetAsync(h, 0, h_bytes, stream);
    hipMemsetAsync(out, 0, (size_t)out_size * sizeof(float), stream);

    const int B = 256;

    // pass 1: counts
    count_kernel<<<(E + B - 1) / B, B, 0, stream>>>(dst, etype, cnt, E);

    // layer 1
    {
        long threads = (long)E * HID_CH;
        long grid = (threads + B - 1) / B;
        l1_edge_kernel<<<(int)grid, B, 0, stream>>>(x, src, dst, etype, cnt, W1, h, E);
    }
    {
        long threads = (long)N * HID_CH;
        long grid = (threads + B - 1) / B;
        l1_node_kernel<<<(int)grid, B, 0, stream>>>(x, root1, b1, h, N);
    }

    // layer 2
    l2_edge_kernel<<<(E + B - 1) / B, B, 0, stream>>>(h, src, dst, etype, cnt, W2, out, E);
    l2_node_kernel<<<(N + B - 1) / B, B, 0, stream>>>(h, root2, b2, out, N);
}

// Round 2
// 447.617 us; speedup vs baseline: 1.9086x; 1.9086x over previous
//
#include <hip/hip_runtime.h>
#include <math.h>

#define N_REL  8
#define IN_CH  16
#define HID_CH 32
#define OUT_CH 2

#define PACK_SHIFT 27
#define PACK_MASK  ((1 << PACK_SHIFT) - 1)

// ---------------------------------------------------------------------------
// Pass 1: per-(dst, rel) edge counts (int atomics, low contention)
// ---------------------------------------------------------------------------
__global__ void count_kernel(const int* __restrict__ dst,
                             const int* __restrict__ rel,
                             int* __restrict__ cnt, int E) {
    int e = blockIdx.x * blockDim.x + threadIdx.x;
    if (e < E) atomicAdd(&cnt[dst[e] * N_REL + rel[e]], 1);
}

// ---------------------------------------------------------------------------
// Scan A: per-block exclusive scan of node degrees (deg = sum_r cnt[n][r]).
// Writes block-local exclusive prefix to rowptr[n], block total to blksum[b].
// ---------------------------------------------------------------------------
__global__ __launch_bounds__(1024) void scan_a_kernel(const int* __restrict__ cnt,
                                                      int* __restrict__ rowptr,
                                                      int* __restrict__ blksum, int N) {
    int n = blockIdx.x * 1024 + threadIdx.x;
    int deg = 0;
    if (n < N) {
#pragma unroll
        for (int r = 0; r < N_REL; ++r) deg += cnt[n * N_REL + r];
    }
    int lane = threadIdx.x & 63;
    int wid  = threadIdx.x >> 6;

    // inclusive scan within wave
    int v = deg;
#pragma unroll
    for (int off = 1; off < 64; off <<= 1) {
        int u = __shfl_up(v, off, 64);
        if (lane >= off) v += u;
    }

    __shared__ int wsum[16];
    if (lane == 63) wsum[wid] = v;
    __syncthreads();

    if (wid == 0) {
        int worig = (lane < 16) ? wsum[lane] : 0;
        int wv = worig;
#pragma unroll
        for (int off = 1; off < 16; off <<= 1) {
            int u = __shfl_up(wv, off, 64);
            if (lane >= off) wv += u;
        }
        if (lane < 16) wsum[lane] = wv - worig;      // exclusive wave offset
        if (lane == 15) blksum[blockIdx.x] = wv;     // block total
    }
    __syncthreads();

    if (n < N) rowptr[n] = (v - deg) + wsum[wid];    // block-local exclusive
}

// ---------------------------------------------------------------------------
// Scan B: serial exclusive scan of the ~98 block sums (single thread; tiny).
// ---------------------------------------------------------------------------
__global__ void scan_b_kernel(int* __restrict__ blksum, int nb,
                              int* __restrict__ rowptr, int N) {
    if (blockIdx.x == 0 && threadIdx.x == 0) {
        int run = 0;
        for (int i = 0; i < nb; ++i) {
            int t = blksum[i];
            blksum[i] = run;
            run += t;
        }
        rowptr[N] = run;   // == E
    }
}

// ---------------------------------------------------------------------------
// Scan C: add block offsets -> global exclusive rowptr.
// ---------------------------------------------------------------------------
__global__ __launch_bounds__(1024) void scan_c_kernel(int* __restrict__ rowptr,
                                                      const int* __restrict__ blksum, int N) {
    int n = blockIdx.x * 1024 + threadIdx.x;
    if (n < N) rowptr[n] += blksum[blockIdx.x];
}

// ---------------------------------------------------------------------------
// Fill CSR: one int atomic per edge; slot value packs src | rel.
// ---------------------------------------------------------------------------
__global__ void fill_kernel(const int* __restrict__ src,
                            const int* __restrict__ dst,
                            const int* __restrict__ rel,
                            const int* __restrict__ rowptr,
                            int* __restrict__ fill,
                            int* __restrict__ csr, int E) {
    int e = blockIdx.x * blockDim.x + threadIdx.x;
    if (e >= E) return;
    int d = dst[e];
    int slot = rowptr[d] + atomicAdd(&fill[d], 1);
    csr[slot] = src[e] | (rel[e] << PACK_SHIFT);
}

// ---------------------------------------------------------------------------
// Layer 1 gather: 32 lanes per node, lane = hidden channel.
// h[n][c] = relu( b1[c] + x[n]@root1[:,c] + sum_e norm_e * (x[src_e]@W1[rel_e])[c] )
// No atomics; h written exactly once.
// ---------------------------------------------------------------------------
__global__ __launch_bounds__(256) void l1_gather_kernel(const float* __restrict__ x,
                                                        const int* __restrict__ csr,
                                                        const int* __restrict__ rowptr,
                                                        const int* __restrict__ cnt,
                                                        const float* __restrict__ W1,
                                                        const float* __restrict__ root1,
                                                        const float* __restrict__ b1,
                                                        float* __restrict__ h, int N) {
    __shared__ float sW[N_REL * IN_CH * HID_CH];   // 16 KB
    for (int i = threadIdx.x; i < N_REL * IN_CH * HID_CH; i += blockDim.x)
        sW[i] = W1[i];
    __syncthreads();

    long gid = (long)blockIdx.x * blockDim.x + threadIdx.x;
    int node = (int)(gid >> 5);
    int c    = (int)(gid & 31);
    if (node >= N) return;

    float acc = b1[c];

    // root term: x[node] @ root1[:, c]
    {
        const float4* xr = (const float4*)(x + (long)node * IN_CH);
        float4 r0 = xr[0], r1 = xr[1], r2 = xr[2], r3 = xr[3];
        const float* wr = root1 + c;
        acc += r0.x * wr[0 * 32] + r0.y * wr[1 * 32] + r0.z * wr[2 * 32] + r0.w * wr[3 * 32]
             + r1.x * wr[4 * 32] + r1.y * wr[5 * 32] + r1.z * wr[6 * 32] + r1.w * wr[7 * 32]
             + r2.x * wr[8 * 32] + r2.y * wr[9 * 32] + r2.z * wr[10 * 32] + r2.w * wr[11 * 32]
             + r3.x * wr[12 * 32] + r3.y * wr[13 * 32] + r3.z * wr[14 * 32] + r3.w * wr[15 * 32];
    }

    int p0 = rowptr[node], p1 = rowptr[node + 1];
    for (int p = p0; p < p1; ++p) {
        int pk = csr[p];                       // broadcast across 32 lanes
        int s  = pk & PACK_MASK;
        int r  = ((unsigned)pk) >> PACK_SHIFT;
        float norm = 1.0f / (float)cnt[node * N_REL + r];

        const float4* xs = (const float4*)(x + (long)s * IN_CH);
        float4 v0 = xs[0], v1 = xs[1], v2 = xs[2], v3 = xs[3];

        const float* w = sW + (r * IN_CH) * HID_CH + c;   // lane-stride 1: conflict-free
        float m;
        m  = v0.x * w[0];    m += v0.y * w[32];   m += v0.z * w[64];   m += v0.w * w[96];
        m += v1.x * w[128];  m += v1.y * w[160];  m += v1.z * w[192];  m += v1.w * w[224];
        m += v2.x * w[256];  m += v2.y * w[288];  m += v2.z * w[320];  m += v2.w * w[352];
        m += v3.x * w[384];  m += v3.y * w[416];  m += v3.z * w[448];  m += v3.w * w[480];
        acc += m * norm;
    }

    h[(long)node * HID_CH + c] = fmaxf(acc, 0.0f);
}

// ---------------------------------------------------------------------------
// Layer 2 gather: 32 lanes per node, lane = hidden channel; shuffle-reduce.
// out[n][:] = log_softmax( b2 + h[n]@root2 + sum_e norm_e * h[src_e]@W2[rel_e] )
// ---------------------------------------------------------------------------
__global__ __launch_bounds__(256) void l2_gather_kernel(const float* __restrict__ h,
                                                        const int* __restrict__ csr,
                                                        const int* __restrict__ rowptr,
                                                        const int* __restrict__ cnt,
                                                        const float* __restrict__ W2,
                                                        const float* __restrict__ root2,
                                                        const float* __restrict__ b2,
                                                        float* __restrict__ out, int N) {
    __shared__ float sW[N_REL * HID_CH * OUT_CH];  // 2 KB
    for (int i = threadIdx.x; i < N_REL * HID_CH * OUT_CH; i += blockDim.x)
        sW[i] = W2[i];
    __syncthreads();

    long gid = (long)blockIdx.x * blockDim.x + threadIdx.x;
    int node = (int)(gid >> 5);
    int c    = (int)(gid & 31);
    if (node >= N) return;

    float o0 = 0.0f, o1 = 0.0f;

    int p0 = rowptr[node], p1 = rowptr[node + 1];
    for (int p = p0; p < p1; ++p) {
        int pk = csr[p];
        int s  = pk & PACK_MASK;
        int r  = ((unsigned)pk) >> PACK_SHIFT;
        float norm = 1.0f / (float)cnt[node * N_REL + r];

        float hv = h[(long)s * HID_CH + c] * norm;   // coalesced 128B per half-wave
        o0 += hv * sW[r * (HID_CH * OUT_CH) + c * OUT_CH + 0];
        o1 += hv * sW[r * (HID_CH * OUT_CH) + c * OUT_CH + 1];
    }

    // root term
    {
        float hr = h[(long)node * HID_CH + c];
        o0 += hr * root2[c * OUT_CH + 0];
        o1 += hr * root2[c * OUT_CH + 1];
    }

    // reduce across the 32 lanes of this half-wave (xor masks < 32 stay in half)
#pragma unroll
    for (int m = 1; m < 32; m <<= 1) {
        o0 += __shfl_xor(o0, m, 64);
        o1 += __shfl_xor(o1, m, 64);
    }

    if (c == 0) {
        o0 += b2[0];
        o1 += b2[1];
        float mx = fmaxf(o0, o1);
        float l  = mx + logf(__expf(o0 - mx) + __expf(o1 - mx));
        out[(long)node * OUT_CH + 0] = o0 - l;
        out[(long)node * OUT_CH + 1] = o1 - l;
    }
}

// ---------------------------------------------------------------------------
extern "C" void kernel_launch(void* const* d_in, const int* in_sizes, int n_in,
                              void* d_out, int out_size, void* d_ws, size_t ws_size,
                              hipStream_t stream) {
    const float* x     = (const float*)d_in[0];
    const int*   eidx  = (const int*)d_in[1];
    const int*   etype = (const int*)d_in[2];
    const float* W1    = (const float*)d_in[3];
    const float* root1 = (const float*)d_in[4];
    const float* b1    = (const float*)d_in[5];
    const float* W2    = (const float*)d_in[6];
    const float* root2 = (const float*)d_in[7];
    const float* b2    = (const float*)d_in[8];
    float* out = (float*)d_out;

    const int N = in_sizes[0] / IN_CH;
    const int E = in_sizes[2];
    const int* src = eidx;
    const int* dst = eidx + E;

    // workspace layout (16B-aligned chunks):
    //   cnt    : N*N_REL ints          (3.2 MB)
    //   rowptr : N+1 ints              (0.4 MB)
    //   fill   : N ints                (0.4 MB)
    //   blksum : nb ints (pad 4096)
    //   csr    : E ints                (6.4 MB)
    //   h      : N*HID_CH floats       (12.8 MB)
    char* wp = (char*)d_ws;
    auto take = [&](size_t bytes) {
        char* p = wp;
        wp += (bytes + 15) & ~(size_t)15;
        return p;
    };
    int*   cnt    = (int*)take((size_t)N * N_REL * sizeof(int));
    int*   rowptr = (int*)take((size_t)(N + 1) * sizeof(int));
    int*   fillc  = (int*)take((size_t)N * sizeof(int));
    int*   blksum = (int*)take(4096 * sizeof(int));
    int*   csr    = (int*)take((size_t)E * sizeof(int));
    float* h      = (float*)take((size_t)N * HID_CH * sizeof(float));

    hipMemsetAsync(cnt, 0, (size_t)N * N_REL * sizeof(int), stream);
    hipMemsetAsync(fillc, 0, (size_t)N * sizeof(int), stream);

    const int B = 256;
    const int nb = (N + 1023) / 1024;

    count_kernel<<<(E + B - 1) / B, B, 0, stream>>>(dst, etype, cnt, E);

    scan_a_kernel<<<nb, 1024, 0, stream>>>(cnt, rowptr, blksum, N);
    scan_b_kernel<<<1, 64, 0, stream>>>(blksum, nb, rowptr, N);
    scan_c_kernel<<<nb, 1024, 0, stream>>>(rowptr, blksum, N);

    fill_kernel<<<(E + B - 1) / B, B, 0, stream>>>(src, dst, etype, rowptr, fillc, csr, E);

    {
        long threads = (long)N * 32;
        int grid = (int)((threads + B - 1) / B);
        l1_gather_kernel<<<grid, B, 0, stream>>>(x, csr, rowptr, cnt, W1, root1, b1, h, N);
        l2_gather_kernel<<<grid, B, 0, stream>>>(h, csr, rowptr, cnt, W2, root2, b2, out, N);
    }
}